// Round 5
// baseline (1479.147 us; speedup 1.0000x reference)
//
#include <hip/hip_runtime.h>
#include <stdint.h>

#define NB   16
#define CIN  32
#define COUT 32
#define HH   256
#define WW   256
#define HWSZ (HH * WW)
#define EPSV 1e-5f
#define NSLOT 6
#define TWD   264      // LDS row words: zero pads at index 3 and 260, data 4..259

typedef int v4i  __attribute__((ext_vector_type(4)));
typedef int v16i __attribute__((ext_vector_type(16)));

// ---------------------------------------------------------------------------
// Kernel 1 (tiny, 1 block): weight pack -> MFMA A-fragments + BN/correction
// tables. wb = sign(sign(w)+0.01): -1 iff w<0, +1 otherwise.
//   afrag[t][lane] = 16 i8 (+-1): o = lane&31, ch = (lane>>5)*16 + e
//   c1f[o]      = 2 * gamma/sqrt(var+eps)
//   c0f[cls][o] = beta - mean*inv - Wsum[cls][o]*inv
// With B in {0,1} (1 iff x>=0, pads/invalid taps = 0): result = acc*c1 + c0.
// ---------------------------------------------------------------------------
__global__ __launch_bounds__(288) void pack_w_kernel(
    const float* __restrict__ wt, const float* __restrict__ gamma,
    const float* __restrict__ beta, const float* __restrict__ rmean,
    const float* __restrict__ rvar, uint4* __restrict__ afrag,
    float* __restrict__ c0f, float* __restrict__ c1f) {
    __shared__ uint32_t pws[COUT * 9];
    const int j = threadIdx.x;                 // 0..287
    if (j < COUT * 9) {
        const int o = j / 9, t = j % 9;
        uint32_t bits = 0;
#pragma unroll
        for (int c = 0; c < CIN; ++c)
            bits |= (wt[(o * CIN + c) * 9 + t] < 0.f) ? (1u << c) : 0u;  // 1 = -1
        pws[j] = bits;
    }
    __syncthreads();
    if (j < 64) {
        const int sh = (j & 32) >> 1;          // channel half 0/16
#pragma unroll
        for (int t = 0; t < 9; ++t) {
            const uint32_t chunk = pws[(j & 31) * 9 + t] >> sh;
            uint32_t w[4];
#pragma unroll
            for (int k = 0; k < 4; ++k) {
                const uint32_t y = (((chunk >> (4 * k)) & 0xFu) * 0x204081u) & 0x01010101u;
                w[k] = (y * 0xFEu) | 0x01010101u;   // bit? 0xFF(-1) : 0x01(+1)
            }
            afrag[t * 64 + j] = make_uint4(w[0], w[1], w[2], w[3]);
        }
    }
    {
        const int cls = j >> 5;                // 0..8
        const int o   = j & 31;
        const int rc = cls / 3, cc = cls % 3;
        int wsum = 0;
#pragma unroll
        for (int dh = 0; dh < 3; ++dh)
#pragma unroll
            for (int dw = 0; dw < 3; ++dw) {
                const bool bad = (rc == 0 && dh == 0) || (rc == 2 && dh == 2) ||
                                 (cc == 0 && dw == 0) || (cc == 2 && dw == 2);
                if (!bad) wsum += 32 - 2 * __popc(pws[o * 9 + dh * 3 + dw]);
            }
        const float inv = gamma[o] * rsqrtf(rvar[o] + EPSV);
        c0f[cls * 32 + o] = beta[o] - rmean[o] * inv - (float)wsum * inv;
        if (cls == 0) c1f[o] = 2.0f * inv;
    }
}

// circular slot index, v in [0, 11]
__device__ __forceinline__ int slot6(int v) { return (v >= NSLOT) ? (v - NSLOT) : v; }

// ---------------------------------------------------------------------------
// Kernel 2: pipelined strip kernel. Block = (n, 8 output rows), 512 threads.
// 6-slot circular LDS buffer of bit-packed rows (bit c = x>=0, pads = 0).
// Per pair-iteration j (output rows h0+2j, h0+2j+1):
//   conv+BN+ReLU+store from slots (2j..2j+3)%6,
//   then extract in-flight prefetch (rows k=2j+4,2j+5) -> LDS,
//   then issue loads for rows k=2j+6,2j+7 (consumed next iter),
//   one barrier per iteration.
// Prefetch task: 1 pixel/thread, 32 channel dword loads (balanced, 32 VGPR).
// ---------------------------------------------------------------------------
__global__ __launch_bounds__(512, 4) void biconv_mfma(
    const uint32_t* __restrict__ x, const uint4* __restrict__ afrag,
    const float* __restrict__ c0f, const float* __restrict__ c1f,
    float* __restrict__ out) {
    const uint32_t bid = blockIdx.x;                      // 0..511
    const uint32_t wg  = ((bid & 7u) << 6) | (bid >> 3);  // bijective XCD chunk
    const int n   = wg >> 5;                              // 0..15
    const int h0  = (wg & 31) << 3;                       // strip base row
    const int tid  = threadIdx.x;
    const int lane = tid & 63;
    const int wave = tid >> 6;

    __shared__ uint32_t tiles[NSLOT][TWD];
    __shared__ float    c0sh[9 * COUT];
    __shared__ float    c1sh[COUT];

    for (int i = tid; i < 9 * COUT; i += 512) c0sh[i] = c0f[i];
    if (tid < COUT) c1sh[tid] = c1f[tid];
    if (tid < NSLOT * 2) tiles[tid >> 1][(tid & 1) ? 260 : 3] = 0u;

    const uint32_t* xn = x + (size_t)n * (CIN * HWSZ);

    // A fragments (identical for all blocks, L2-hot)
    v4i af[9];
#pragma unroll
    for (int t = 0; t < 9; ++t)
        af[t] = *reinterpret_cast<const v4i*>(&afrag[t * 64 + lane]);

    // ---- prologue: pack rows k=0..3 (2 tasks/thread, 1 pixel each) ----
    const int mypx = tid & 255;
#pragma unroll
    for (int it = 0; it < 2; ++it) {
        const int k  = (tid >> 8) + it * 2;    // 0..3
        const int hr = h0 - 1 + k;             // only k=0,h0=0 can be OOB (<0)
        uint32_t b = 0;
        if (hr >= 0) {
            const uint32_t* xp = xn + (size_t)hr * WW + mypx;
#pragma unroll
            for (int c = 0; c < CIN; ++c) b |= (xp[(size_t)c * HWSZ] >> 31) << c;
            b = ~b;                            // bit = (x >= 0)
        }
        tiles[k][mypx + 4] = b;
    }
    // ---- issue prefetch for k=4,5 (always in-bounds: hr <= 252) ----
    uint32_t pf[CIN];
    {
        const int hr = h0 - 1 + 4 + (tid >> 8);
        const uint32_t* xp = xn + (size_t)hr * WW + mypx;
#pragma unroll
        for (int c = 0; c < CIN; ++c) pf[c] = xp[(size_t)c * HWSZ];
    }
    __syncthreads();

    // ---- main loop: 4 row-pairs ----
    const int rsel = wave >> 2;                 // row within pair
    const int p0   = (wave & 3) << 6;           // pixel base of this wave
    const int shv  = (lane & 32) >> 1;          // channel half for B expansion
    const int og   = (lane >> 5) << 2;          // C/D row offset 0/4

#pragma unroll
    for (int j = 0; j < 4; ++j) {
        const int h  = h0 + 2 * j + rsel;
        const int rc = (h == 0) ? 0 : ((h == HH - 1) ? 2 : 1);
        const int kbase = 2 * j + rsel;         // input k for dh=0
#pragma unroll
        for (int tw = 0; tw < 2; ++tw) {
            const int pixel = p0 + (tw << 5) + (lane & 31);
            v16i acc = {0};
#pragma unroll
            for (int dh = 0; dh < 3; ++dh) {
                const uint32_t* trow = tiles[slot6(kbase + dh)];
#pragma unroll
                for (int dw = 0; dw < 3; ++dw) {
                    const uint32_t h16 = trow[pixel + 3 + dw] >> shv;
                    v4i b;
                    b.x = (int)(((( h16       ) & 0xFu) * 0x204081u) & 0x01010101u);
                    b.y = (int)((((h16 >> 4  ) & 0xFu) * 0x204081u) & 0x01010101u);
                    b.z = (int)((((h16 >> 8  ) & 0xFu) * 0x204081u) & 0x01010101u);
                    b.w = (int)((((h16 >> 12 ) & 0xFu) * 0x204081u) & 0x01010101u);
                    acc = __builtin_amdgcn_mfma_i32_32x32x32_i8(af[dh * 3 + dw], b,
                                                                acc, 0, 0, 0);
                }
            }
            const int ccls = (pixel == 0) ? 0 : ((pixel == WW - 1) ? 2 : 1);
            const float* c0b = &c0sh[(rc * 3 + ccls) * 32];
            float* outp = out + (size_t)n * (COUT * HWSZ) + (size_t)h * WW + pixel;
#pragma unroll
            for (int e = 0; e < 16; ++e) {
                const int o = (e & 3) + ((e >> 2) << 3) + og;
                const float v = fmaf((float)acc[e], c1sh[o], c0b[o]);
                __builtin_nontemporal_store(v > 0.f ? v : 0.f,
                                            outp + (size_t)o * HWSZ);
            }
        }
        // ---- pipeline: land prefetched rows, issue next ----
        if (j < 3) {
            const int kw  = 2 * j + 4 + (tid >> 8);
            const int hrw = h0 - 1 + kw;        // OOB only for kw=9 on last strip
            uint32_t b = 0;
            if (hrw < HH) {
#pragma unroll
                for (int c = 0; c < CIN; ++c) b |= (pf[c] >> 31) << c;
                b = ~b;
            }
            tiles[slot6(kw)][mypx + 4] = b;
            if (j < 2) {
                const int kn  = 2 * j + 6 + (tid >> 8);
                const int hrn = h0 - 1 + kn;
                if (hrn < HH) {
                    const uint32_t* xp = xn + (size_t)hrn * WW + mypx;
#pragma unroll
                    for (int c = 0; c < CIN; ++c) pf[c] = xp[(size_t)c * HWSZ];
                }
            }
            __syncthreads();
        }
    }
}

// ---------------------------------------------------------------------------
extern "C" void kernel_launch(void* const* d_in, const int* in_sizes, int n_in,
                              void* d_out, int out_size, void* d_ws, size_t ws_size,
                              hipStream_t stream) {
    const float* x     = (const float*)d_in[0];
    const float* wt    = (const float*)d_in[1];
    const float* gamma = (const float*)d_in[2];
    const float* beta  = (const float*)d_in[3];
    const float* rmean = (const float*)d_in[4];
    const float* rvar  = (const float*)d_in[5];
    float* out = (float*)d_out;

    uint4* afrag = (uint4*)d_ws;                           // 9*64*16 = 9216 B
    float* c0f   = (float*)((char*)d_ws + 9216);           // 288 floats
    float* c1f   = c0f + 288;                              // 32 floats

    pack_w_kernel<<<dim3(1), dim3(288), 0, stream>>>(wt, gamma, beta, rmean,
                                                     rvar, afrag, c0f, c1f);
    biconv_mfma<<<dim3(NB * HH / 8), dim3(512), 0, stream>>>(
        (const uint32_t*)x, afrag, c0f, c1f, out);
}

// Round 6
// 50.423 us; speedup vs baseline: 29.3348x; 29.3348x over previous
//
#include <hip/hip_runtime.h>
#include <stdint.h>

#define NB   16
#define CIN  32
#define COUT 32
#define HH   256
#define WW   256
#define HWSZ (HH * WW)
#define EPSV 1e-5f
#define TWD  264     // LDS row words: zero pads at index 3 and 260, data at 4..259

typedef int v4i  __attribute__((ext_vector_type(4)));
typedef int v16i __attribute__((ext_vector_type(16)));

// ---------------------------------------------------------------------------
// Kernel 1 (tiny, 1 block): weight pack -> MFMA A-fragments + BN/correction
// tables. wb = sign(sign(w)+0.01): -1 iff w<0, +1 otherwise.
//   afrag[t*64+lane] = 16 i8 (+-1): o = lane&31, ch = (lane>>5)*16 + e
//   c0f[cls*32+o] = beta - mean*inv - Wsum[cls][o]*inv
//   c0f[288+o]    = 2 * gamma/sqrt(var+eps)   (c1, appended)
// With B in {0,1} (1 iff x>=0, pads/invalid taps = 0): result = acc*c1 + c0.
// ---------------------------------------------------------------------------
__global__ __launch_bounds__(288) void pack_w_kernel(
    const float* __restrict__ wt, const float* __restrict__ gamma,
    const float* __restrict__ beta, const float* __restrict__ rmean,
    const float* __restrict__ rvar, uint4* __restrict__ afrag,
    float* __restrict__ c0f) {
    __shared__ uint32_t pws[COUT * 9];
    const int j = threadIdx.x;                 // 0..287
    if (j < COUT * 9) {
        const int o = j / 9, t = j % 9;
        uint32_t bits = 0;
#pragma unroll
        for (int c = 0; c < CIN; ++c)
            bits |= (wt[(o * CIN + c) * 9 + t] < 0.f) ? (1u << c) : 0u;  // 1 = -1
        pws[j] = bits;
    }
    __syncthreads();
    if (j < 64) {
        const int sh = (j & 32) >> 1;          // channel half 0/16
#pragma unroll
        for (int t = 0; t < 9; ++t) {
            const uint32_t chunk = pws[(j & 31) * 9 + t] >> sh;
            uint32_t w[4];
#pragma unroll
            for (int k = 0; k < 4; ++k) {
                const uint32_t y = (((chunk >> (4 * k)) & 0xFu) * 0x204081u) & 0x01010101u;
                w[k] = (y * 0xFEu) | 0x01010101u;   // bit? 0xFF(-1) : 0x01(+1)
            }
            afrag[t * 64 + j] = make_uint4(w[0], w[1], w[2], w[3]);
        }
    }
    {
        const int cls = j >> 5;                // 0..8
        const int o   = j & 31;
        const int rc = cls / 3, cc = cls % 3;
        int wsum = 0;
#pragma unroll
        for (int dh = 0; dh < 3; ++dh)
#pragma unroll
            for (int dw = 0; dw < 3; ++dw) {
                const bool bad = (rc == 0 && dh == 0) || (rc == 2 && dh == 2) ||
                                 (cc == 0 && dw == 0) || (cc == 2 && dw == 2);
                if (!bad) wsum += 32 - 2 * __popc(pws[o * 9 + dh * 3 + dw]);
            }
        const float inv = gamma[o] * rsqrtf(rvar[o] + EPSV);
        c0f[cls * 32 + o] = beta[o] - rmean[o] * inv - (float)wsum * inv;
        if (cls == 0) c0f[288 + o] = 2.0f * inv;
    }
}

// ---------------------------------------------------------------------------
// Kernel 2: fused binarize + implicit-GEMM i8-MFMA conv + BN + ReLU.
// One block per (n, h): 4096 blocks, 256 threads (round-2 TLP shape).
// Threads 0..191 pack the 3 halo rows (bit c = x>=0, uint4 loads); threads
// 192..255 stage A-fragments + BN tables into LDS. Conv is tap-outer with
// two accumulators (per-wave 64-pixel span); the A-fragment is read per tap
// from LDS so only one is register-resident at a time (VGPR control).
// ---------------------------------------------------------------------------
__global__ __launch_bounds__(256, 6) void biconv_mfma(
    const uint32_t* __restrict__ x, const uint4* __restrict__ afrag,
    const float* __restrict__ c0f, float* __restrict__ out) {
    const uint32_t bid = blockIdx.x;                       // 0..4095
    const uint32_t wg  = ((bid & 7u) << 9) | (bid >> 3);   // bijective XCD chunk
    const int n   = wg >> 8;                               // 0..15
    const int h   = wg & 255;                              // 0..255
    const int tid  = threadIdx.x;
    const int lane = tid & 63;
    const int wave = tid >> 6;

    __shared__ uint32_t tiles[3][TWD];
    __shared__ uint4    afsh[9 * 64];     // 9216 B
    __shared__ float    csh[320];         // c0[0..287], c1[288..319]

    if (tid < 192) {
        // ---- pack 3 halo rows: r = tid>>6, quad q = tid&63 ----
        const int r  = tid >> 6;
        const int q  = tid & 63;
        const int hr = h - 1 + r;
        uint32_t b0 = 0, b1 = 0, b2 = 0, b3 = 0;
        if (hr >= 0 && hr < HH) {
            const uint32_t* xp = x + (size_t)n * (CIN * HWSZ) + (size_t)hr * WW + (q << 2);
#pragma unroll
            for (int c = 0; c < CIN; ++c) {
                const uint4 v = *reinterpret_cast<const uint4*>(xp + (size_t)c * HWSZ);
                b0 |= (v.x >> 31) << c;
                b1 |= (v.y >> 31) << c;
                b2 |= (v.z >> 31) << c;
                b3 |= (v.w >> 31) << c;
            }
            b0 = ~b0; b1 = ~b1; b2 = ~b2; b3 = ~b3;   // bit = (x >= 0)
        }
        *reinterpret_cast<uint4*>(&tiles[r][(q << 2) + 4]) = make_uint4(b0, b1, b2, b3);
    } else {
        const int t2 = tid - 192;          // 0..63
#pragma unroll
        for (int k = 0; k < 9; ++k) afsh[t2 + 64 * k] = afrag[t2 + 64 * k];
#pragma unroll
        for (int k = 0; k < 5; ++k) csh[t2 + 64 * k] = c0f[t2 + 64 * k];
        if (t2 < 6) tiles[t2 >> 1][(t2 & 1) ? 260 : 3] = 0u;
    }
    __syncthreads();

    // ---- conv: wave handles 64 consecutive pixels (two 32-px tiles) ----
    const int l31 = lane & 31;
    const int shv = (lane & 32) >> 1;      // channel half for B expansion
    const int og  = (lane >> 5) << 2;      // C/D row offset 0/4
    const int pA  = (wave << 6) + l31;     // tile A pixel
    const int pB  = pA + 32;               // tile B pixel

    v16i acc0 = {0}, acc1 = {0};
#pragma unroll
    for (int dh = 0; dh < 3; ++dh) {
        const uint32_t* trow = &tiles[dh][0];
#pragma unroll
        for (int dw = 0; dw < 3; ++dw) {
            const v4i a = *reinterpret_cast<const v4i*>(&afsh[(dh * 3 + dw) * 64 + lane]);
            const uint32_t hA = trow[pA + 3 + dw] >> shv;
            const uint32_t hB = trow[pB + 3 + dw] >> shv;
            v4i b;
            b.x = (int)((( hA        & 0xFu) * 0x204081u) & 0x01010101u);
            b.y = (int)((((hA >> 4)  & 0xFu) * 0x204081u) & 0x01010101u);
            b.z = (int)((((hA >> 8)  & 0xFu) * 0x204081u) & 0x01010101u);
            b.w = (int)((((hA >> 12) & 0xFu) * 0x204081u) & 0x01010101u);
            acc0 = __builtin_amdgcn_mfma_i32_32x32x32_i8(a, b, acc0, 0, 0, 0);
            b.x = (int)((( hB        & 0xFu) * 0x204081u) & 0x01010101u);
            b.y = (int)((((hB >> 4)  & 0xFu) * 0x204081u) & 0x01010101u);
            b.z = (int)((((hB >> 8)  & 0xFu) * 0x204081u) & 0x01010101u);
            b.w = (int)((((hB >> 12) & 0xFu) * 0x204081u) & 0x01010101u);
            acc1 = __builtin_amdgcn_mfma_i32_32x32x32_i8(a, b, acc1, 0, 0, 0);
        }
    }

    // ---- epilogue: C/D row = (e&3)+8*(e>>2)+og, col = pixel ----
    const int rc   = (h == 0) ? 0 : ((h == HH - 1) ? 2 : 1);
    const int ccA  = (pA == 0) ? 0 : ((pA == WW - 1) ? 2 : 1);
    const int ccB  = (pB == WW - 1) ? 2 : 1;      // pB >= 32, never 0
    const float* c0A = &csh[(rc * 3 + ccA) * 32];
    const float* c0B = &csh[(rc * 3 + ccB) * 32];
    const float* c1  = &csh[288];
    float* outp = out + (size_t)n * (COUT * HWSZ) + (size_t)h * WW;
#pragma unroll
    for (int e = 0; e < 16; ++e) {
        const int o = (e & 3) + ((e >> 2) << 3) + og;
        const float vA = fmaf((float)acc0[e], c1[o], c0A[o]);
        const float vB = fmaf((float)acc1[e], c1[o], c0B[o]);
        __builtin_nontemporal_store(vA > 0.f ? vA : 0.f, outp + (size_t)o * HWSZ + pA);
        __builtin_nontemporal_store(vB > 0.f ? vB : 0.f, outp + (size_t)o * HWSZ + pB);
    }
}

// ---------------------------------------------------------------------------
extern "C" void kernel_launch(void* const* d_in, const int* in_sizes, int n_in,
                              void* d_out, int out_size, void* d_ws, size_t ws_size,
                              hipStream_t stream) {
    const float* x     = (const float*)d_in[0];
    const float* wt    = (const float*)d_in[1];
    const float* gamma = (const float*)d_in[2];
    const float* beta  = (const float*)d_in[3];
    const float* rmean = (const float*)d_in[4];
    const float* rvar  = (const float*)d_in[5];
    float* out = (float*)d_out;

    uint4* afrag = (uint4*)d_ws;                           // 9*64*16 = 9216 B
    float* c0f   = (float*)((char*)d_ws + 9216);           // 288 + 32 floats

    pack_w_kernel<<<dim3(1), dim3(288), 0, stream>>>(wt, gamma, beta, rmean,
                                                     rvar, afrag, c0f);
    biconv_mfma<<<dim3(NB * HH), dim3(256), 0, stream>>>(
        (const uint32_t*)x, afrag, c0f, out);
}